// Round 6
// baseline (693.808 us; speedup 1.0000x reference)
//
#include <hip/hip_runtime.h>
#include <hip/hip_cooperative_groups.h>

namespace cg = cooperative_groups;

#define BN_EPS 0.001f
#define CAP 32   // deg = 1 + Poisson(~9); P(deg >= 32) ~ 1e-22 -> safe

typedef __attribute__((ext_vector_type(8))) short bf16x8;
typedef __attribute__((ext_vector_type(4))) float f32x4;

__device__ __forceinline__ unsigned short f2bf(float f) {
  unsigned u = __float_as_uint(f);
  u += 0x7fffu + ((u >> 16) & 1u);
  return (unsigned short)(u >> 16);
}
__device__ __forceinline__ unsigned scale2(unsigned u, float s) {
  float lo = __uint_as_float(u << 16) * s;
  float hi = __uint_as_float(u & 0xffff0000u) * s;
  return (((unsigned)f2bf(hi)) << 16) | (unsigned)f2bf(lo);
}

// =====================================================================
// ONE cooperative kernel: zero-cnt | scatter+gemm | scale | agg+BN
// Kills ~10us/dispatch overhead x4 and the memset dispatch.
// =====================================================================
__global__ __launch_bounds__(256, 4) void k_all(
    const float* __restrict__ X, const float* __restrict__ W,
    const float* __restrict__ B, const float* __restrict__ gamma,
    const float* __restrict__ beta, const float* __restrict__ mean,
    const float* __restrict__ var, const int2* __restrict__ ei,
    unsigned short* __restrict__ hb, unsigned short* __restrict__ hbs,
    int* __restrict__ ell_t, int* __restrict__ cnt,
    float* __restrict__ out, int N, int E, int use_hbs) {
  __shared__ float WtF[4096];   // 16 KB: phase1 = swizzled Wt; phase3 = dst/cnt overlay
  cg::grid_group gg = cg::this_grid();
  int tid = threadIdx.x;
  int bid = blockIdx.x;
  int nb  = gridDim.x;

  // ---- phase 0: zero cnt ----
  for (int i = bid * 256 + tid; i < N; i += nb * 256) cnt[i] = 0;
  gg.sync();

  // ---- phase 1: scatter + MFMA gemm, 5:2 interleaved, grid-stride ----
  // stage W once per block (bf16, transposed Wt[col][k], XOR-swizzled)
  char* Wt = (char*)WtF;
  {
    const float4* W4 = (const float4*)W;
    for (int i = tid; i < 2048; i += 256) {
      float4 v = W4[i];
      int k = i >> 4;
      int col0 = (i & 15) << 2;
      int kb2 = k << 1;
      *(unsigned short*)(Wt + (((col0 + 0) << 8) | (kb2 ^ (((col0 + 0) & 7) << 4)))) = f2bf(v.x);
      *(unsigned short*)(Wt + (((col0 + 1) << 8) | (kb2 ^ (((col0 + 1) & 7) << 4)))) = f2bf(v.y);
      *(unsigned short*)(Wt + (((col0 + 2) << 8) | (kb2 ^ (((col0 + 2) & 7) << 4)))) = f2bf(v.z);
      *(unsigned short*)(Wt + (((col0 + 3) << 8) | (kb2 ^ (((col0 + 3) & 7) << 4)))) = f2bf(v.w);
    }
  }
  __syncthreads();

  int Gg = (N + 63) >> 6;
  int Gs = (E + 255) >> 8;
  int g7 = (Gg + 1) >> 1;
  int g5 = (Gs + 4) / 5;
  int groups = (g7 > g5) ? g7 : g5;
  int total = groups * 7;

  int lane = tid & 63;
  int w = tid >> 6;
  int l15 = lane & 15;
  int lk = lane >> 4;

  for (int u = bid; u < total; u += nb) {
    int g = u / 7, r = u % 7;
    if (r >= 2) {
      // scatter: histogram + placement in ONE atomic, 1 edge/thread
      int chunk = g * 5 + (r - 2);
      if (chunk < Gs) {
        int e = chunk * 256 + tid;
        if (e < E) {
          int2 sd = ei[e];
          int pos = atomicAdd(&cnt[sd.x], 1);
          if (pos < CAP) ell_t[(size_t)pos * N + sd.x] = sd.y;
        }
      }
    } else {
      // gemm: hb = bf16(X@W + b), 64x64 tile (Wt is read-only; no syncthreads needed)
      int tile = g * 2 + r;
      if (tile < Gg) {
        int row0 = tile * 64;
        int rA = row0 + w * 16 + l15;
        bool rowok = rA < N;
        const float* xp = X + (size_t)rA * 128 + (lk << 3);

        f32x4 acc[4];
        #pragma unroll
        for (int n = 0; n < 4; ++n) {
          float bv = B[(n << 4) + l15];
          acc[n] = (f32x4){bv, bv, bv, bv};
        }
        #pragma unroll
        for (int kb = 0; kb < 4; ++kb) {
          bf16x8 af = {0, 0, 0, 0, 0, 0, 0, 0};
          if (rowok) {
            float4 x0 = *(const float4*)(xp + kb * 32);
            float4 x1 = *(const float4*)(xp + kb * 32 + 4);
            af[0] = (short)f2bf(x0.x); af[1] = (short)f2bf(x0.y);
            af[2] = (short)f2bf(x0.z); af[3] = (short)f2bf(x0.w);
            af[4] = (short)f2bf(x1.x); af[5] = (short)f2bf(x1.y);
            af[6] = (short)f2bf(x1.z); af[7] = (short)f2bf(x1.w);
          }
          int kbyte = (kb << 6) | (lk << 4);
          #pragma unroll
          for (int n = 0; n < 4; ++n) {
            int col = (n << 4) + l15;
            bf16x8 bfr = *(const bf16x8*)(Wt + ((col << 8) | (kbyte ^ ((col & 7) << 4))));
            acc[n] = __builtin_amdgcn_mfma_f32_16x16x32_bf16(af, bfr, acc[n], 0, 0, 0);
          }
        }
        // C/D layout (verified m89/m91): col = lane&15, row = (lane>>4)*4 + reg
        int rbase = row0 + w * 16 + (lk << 2);
        #pragma unroll
        for (int n = 0; n < 4; ++n) {
          #pragma unroll
          for (int q = 0; q < 4; ++q) {
            int row = rbase + q;
            if (row < N) hb[(size_t)row * 64 + (n << 4) + l15] = f2bf(acc[n][q]);
          }
        }
      }
    }
  }
  __threadfence();
  gg.sync();

  // ---- phase 2: hbs = bf16(rsqrt(deg) * hb) ----
  if (use_hbs) {
    const unsigned* hb32r = (const unsigned*)hb;
    unsigned* hbs32w = (unsigned*)hbs;
    int tot = N * 8;
    for (int t = bid * 256 + tid; t < tot; t += nb * 256) {
      int node = t >> 3;
      int q = t & 7;
      int c = cnt[node];
      float s = rsqrtf((float)((c > 0) ? c : 1));
      uint4 v = ((const uint4*)(hb32r + (size_t)node * 32))[q];
      v.x = scale2(v.x, s); v.y = scale2(v.y, s);
      v.z = scale2(v.z, s); v.w = scale2(v.w, s);
      ((uint4*)(hbs32w + (size_t)node * 32))[q] = v;
    }
  }
  __threadfence();
  gg.sync();

  // ---- phase 3: aggregate + self + BN (64 nodes/block-tile, grid-stride) ----
  int* lds_dst = (int*)WtF;             // CAP*64 ints = 8 KB
  int* lds_cnt = ((int*)WtF) + CAP * 64;
  const unsigned* hb32 = (const unsigned*)hb;
  const unsigned* hbs32 = (const unsigned*)hbs;
  int hw = tid >> 5;
  int fp = tid & 31;

  float2 gm = *(const float2*)&gamma[fp * 2];
  float2 bt = *(const float2*)&beta[fp * 2];
  float2 mn = *(const float2*)&mean[fp * 2];
  float2 vr = *(const float2*)&var[fp * 2];
  float gsx = gm.x * rsqrtf(vr.x + BN_EPS);
  float gsy = gm.y * rsqrtf(vr.y + BN_EPS);

  int Ga = (N + 63) >> 6;
  for (int tile = bid; tile < Ga; tile += nb) {
    int node0 = tile << 6;
    if (tid < 64) {
      int n = node0 + tid;
      lds_cnt[tid] = (n < N) ? cnt[n] : 0;
    }
    for (int i = tid; i < CAP * 64; i += 256) {
      int j = i & 63;
      int p = i >> 6;
      int n = node0 + j;
      lds_dst[i] = (n < N) ? ell_t[(size_t)p * N + n] : 0;
    }
    __syncthreads();

    #pragma unroll 2
    for (int t = 0; t < 8; ++t) {
      int j = hw * 8 + t;
      int node = node0 + j;
      if (node < N) {
        int c0 = lds_cnt[j];
        int c = (c0 < CAP) ? c0 : CAP;
        unsigned us = hb32[(size_t)node * 32 + fp];   // self row, issue early

        float ax = 0.f, ay = 0.f;
        if (use_hbs) {
          int q = 0;
          for (; q + 8 <= c; q += 8) {
            int d[8];
            #pragma unroll
            for (int i = 0; i < 8; ++i) {
              int dr = lds_dst[(q + i) * 64 + j];
              d[i] = ((unsigned)dr < (unsigned)N) ? dr : 0;
            }
            unsigned u[8];
            #pragma unroll
            for (int i = 0; i < 8; ++i) u[i] = hbs32[(size_t)d[i] * 32 + fp];
            #pragma unroll
            for (int i = 0; i < 8; ++i) {
              ax += __uint_as_float(u[i] << 16);
              ay += __uint_as_float(u[i] & 0xffff0000u);
            }
          }
          if (q + 4 <= c) {
            int d0 = lds_dst[(q + 0) * 64 + j]; d0 = ((unsigned)d0 < (unsigned)N) ? d0 : 0;
            int d1 = lds_dst[(q + 1) * 64 + j]; d1 = ((unsigned)d1 < (unsigned)N) ? d1 : 0;
            int d2 = lds_dst[(q + 2) * 64 + j]; d2 = ((unsigned)d2 < (unsigned)N) ? d2 : 0;
            int d3 = lds_dst[(q + 3) * 64 + j]; d3 = ((unsigned)d3 < (unsigned)N) ? d3 : 0;
            unsigned u0 = hbs32[(size_t)d0 * 32 + fp];
            unsigned u1 = hbs32[(size_t)d1 * 32 + fp];
            unsigned u2 = hbs32[(size_t)d2 * 32 + fp];
            unsigned u3 = hbs32[(size_t)d3 * 32 + fp];
            ax += __uint_as_float(u0 << 16); ay += __uint_as_float(u0 & 0xffff0000u);
            ax += __uint_as_float(u1 << 16); ay += __uint_as_float(u1 & 0xffff0000u);
            ax += __uint_as_float(u2 << 16); ay += __uint_as_float(u2 & 0xffff0000u);
            ax += __uint_as_float(u3 << 16); ay += __uint_as_float(u3 & 0xffff0000u);
            q += 4;
          }
          for (; q < c; ++q) {
            int dq = lds_dst[q * 64 + j];
            dq = ((unsigned)dq < (unsigned)N) ? dq : 0;
            unsigned u = hbs32[(size_t)dq * 32 + fp];
            ax += __uint_as_float(u << 16);
            ay += __uint_as_float(u & 0xffff0000u);
          }
        } else {
          int q = 0;
          for (; q + 4 <= c; q += 4) {
            int d0 = lds_dst[(q + 0) * 64 + j]; d0 = ((unsigned)d0 < (unsigned)N) ? d0 : 0;
            int d1 = lds_dst[(q + 1) * 64 + j]; d1 = ((unsigned)d1 < (unsigned)N) ? d1 : 0;
            int d2 = lds_dst[(q + 2) * 64 + j]; d2 = ((unsigned)d2 < (unsigned)N) ? d2 : 0;
            int d3 = lds_dst[(q + 3) * 64 + j]; d3 = ((unsigned)d3 < (unsigned)N) ? d3 : 0;
            float s0 = rsqrtf((float)max(cnt[d0], 1));
            float s1 = rsqrtf((float)max(cnt[d1], 1));
            float s2 = rsqrtf((float)max(cnt[d2], 1));
            float s3 = rsqrtf((float)max(cnt[d3], 1));
            unsigned u0 = hb32[(size_t)d0 * 32 + fp];
            unsigned u1 = hb32[(size_t)d1 * 32 + fp];
            unsigned u2 = hb32[(size_t)d2 * 32 + fp];
            unsigned u3 = hb32[(size_t)d3 * 32 + fp];
            ax = fmaf(s0, __uint_as_float(u0 << 16), ax);
            ay = fmaf(s0, __uint_as_float(u0 & 0xffff0000u), ay);
            ax = fmaf(s1, __uint_as_float(u1 << 16), ax);
            ay = fmaf(s1, __uint_as_float(u1 & 0xffff0000u), ay);
            ax = fmaf(s2, __uint_as_float(u2 << 16), ax);
            ay = fmaf(s2, __uint_as_float(u2 & 0xffff0000u), ay);
            ax = fmaf(s3, __uint_as_float(u3 << 16), ax);
            ay = fmaf(s3, __uint_as_float(u3 & 0xffff0000u), ay);
          }
          for (; q < c; ++q) {
            int dq = lds_dst[q * 64 + j];
            dq = ((unsigned)dq < (unsigned)N) ? dq : 0;
            float sq = rsqrtf((float)max(cnt[dq], 1));
            unsigned u = hb32[(size_t)dq * 32 + fp];
            ax = fmaf(sq, __uint_as_float(u << 16), ax);
            ay = fmaf(sq, __uint_as_float(u & 0xffff0000u), ay);
          }
        }

        float hx = __uint_as_float(us << 16);
        float hy = __uint_as_float(us & 0xffff0000u);
        float degf = (float)c0;
        float isd_n = rsqrtf((float)((c0 > 0) ? c0 : 1));
        float rx = 0.5f * (isd_n * ax + degf * hx);
        float ry = 0.5f * (isd_n * ay + degf * hy);

        float2 o;
        o.x = (rx - mn.x) * gsx + bt.x;
        o.y = (ry - mn.y) * gsy + bt.y;
        *(float2*)&out[(size_t)node * 64 + fp * 2] = o;
      }
    }
    __syncthreads();
  }
}

// =====================================================================
// Fallback path (round-5 structure) if cooperative launch is unavailable
// =====================================================================
__global__ __launch_bounds__(256) void k_fused(
    const float* __restrict__ X, const float* __restrict__ W,
    const float* __restrict__ B, unsigned short* __restrict__ hb, int N, int Gg,
    const int2* __restrict__ ei, int* __restrict__ cnt,
    int* __restrict__ ell_t, int E, int Gs) {
  __shared__ float WtF[4096];
  int g = blockIdx.x / 7;
  int r = blockIdx.x % 7;
  int tid = threadIdx.x;

  if (r >= 2) {
    int chunk = g * 5 + (r - 2);
    if (chunk >= Gs) return;
    int e = chunk * 256 + tid;
    if (e < E) {
      int2 sd = ei[e];
      int pos = atomicAdd(&cnt[sd.x], 1);
      if (pos < CAP) ell_t[(size_t)pos * N + sd.x] = sd.y;
    }
    return;
  }

  int tile = g * 2 + r;
  if (tile >= Gg) return;

  char* Wt = (char*)WtF;
  const float4* W4 = (const float4*)W;
  for (int i = tid; i < 2048; i += 256) {
    float4 v = W4[i];
    int k = i >> 4;
    int col0 = (i & 15) << 2;
    int kb2 = k << 1;
    *(unsigned short*)(Wt + (((col0 + 0) << 8) | (kb2 ^ (((col0 + 0) & 7) << 4)))) = f2bf(v.x);
    *(unsigned short*)(Wt + (((col0 + 1) << 8) | (kb2 ^ (((col0 + 1) & 7) << 4)))) = f2bf(v.y);
    *(unsigned short*)(Wt + (((col0 + 2) << 8) | (kb2 ^ (((col0 + 2) & 7) << 4)))) = f2bf(v.z);
    *(unsigned short*)(Wt + (((col0 + 3) << 8) | (kb2 ^ (((col0 + 3) & 7) << 4)))) = f2bf(v.w);
  }
  __syncthreads();

  int lane = tid & 63;
  int w = tid >> 6;
  int l15 = lane & 15;
  int lk = lane >> 4;

  int row0 = tile * 64;
  int rA = row0 + w * 16 + l15;
  bool rowok = rA < N;
  const float* xp = X + (size_t)rA * 128 + (lk << 3);

  f32x4 acc[4];
  #pragma unroll
  for (int n = 0; n < 4; ++n) {
    float bv = B[(n << 4) + l15];
    acc[n] = (f32x4){bv, bv, bv, bv};
  }
  #pragma unroll
  for (int kb = 0; kb < 4; ++kb) {
    bf16x8 af = {0, 0, 0, 0, 0, 0, 0, 0};
    if (rowok) {
      float4 x0 = *(const float4*)(xp + kb * 32);
      float4 x1 = *(const float4*)(xp + kb * 32 + 4);
      af[0] = (short)f2bf(x0.x); af[1] = (short)f2bf(x0.y);
      af[2] = (short)f2bf(x0.z); af[3] = (short)f2bf(x0.w);
      af[4] = (short)f2bf(x1.x); af[5] = (short)f2bf(x1.y);
      af[6] = (short)f2bf(x1.z); af[7] = (short)f2bf(x1.w);
    }
    int kbyte = (kb << 6) | (lk << 4);
    #pragma unroll
    for (int n = 0; n < 4; ++n) {
      int col = (n << 4) + l15;
      bf16x8 bfr = *(const bf16x8*)(Wt + ((col << 8) | (kbyte ^ ((col & 7) << 4))));
      acc[n] = __builtin_amdgcn_mfma_f32_16x16x32_bf16(af, bfr, acc[n], 0, 0, 0);
    }
  }
  int rbase = row0 + w * 16 + (lk << 2);
  #pragma unroll
  for (int n = 0; n < 4; ++n) {
    #pragma unroll
    for (int q = 0; q < 4; ++q) {
      int row = rbase + q;
      if (row < N) hb[(size_t)row * 64 + (n << 4) + l15] = f2bf(acc[n][q]);
    }
  }
}

__global__ __launch_bounds__(256) void k_scale(const unsigned int* __restrict__ hb32,
                                               const int* __restrict__ cnt,
                                               unsigned int* __restrict__ hbs32, int N) {
  int t = blockIdx.x * 256 + threadIdx.x;
  int node = t >> 3;
  int q = t & 7;
  if (node >= N) return;
  int c = cnt[node];
  float s = rsqrtf((float)((c > 0) ? c : 1));
  uint4 v = ((const uint4*)(hb32 + (size_t)node * 32))[q];
  v.x = scale2(v.x, s); v.y = scale2(v.y, s);
  v.z = scale2(v.z, s); v.w = scale2(v.w, s);
  ((uint4*)(hbs32 + (size_t)node * 32))[q] = v;
}

__global__ __launch_bounds__(256) void k_agg2(const int* __restrict__ cnt,
                                              const int* __restrict__ ell_t,
                                              const unsigned int* __restrict__ hb32,
                                              const unsigned int* __restrict__ hbs32,
                                              const float* __restrict__ gamma,
                                              const float* __restrict__ beta,
                                              const float* __restrict__ mean,
                                              const float* __restrict__ var,
                                              float* __restrict__ out, int N) {
  __shared__ int lds_dst[CAP * 64];
  __shared__ int lds_cnt[64];
  int tid = threadIdx.x;
  int node0 = blockIdx.x * 64;

  if (tid < 64) {
    int n = node0 + tid;
    lds_cnt[tid] = (n < N) ? cnt[n] : 0;
  }
  for (int i = tid; i < CAP * 64; i += 256) {
    int j = i & 63;
    int p = i >> 6;
    int n = node0 + j;
    lds_dst[i] = (n < N) ? ell_t[(size_t)p * N + n] : 0;
  }
  __syncthreads();

  int hw = tid >> 5;
  int fp = tid & 31;
  float2 gm = *(const float2*)&gamma[fp * 2];
  float2 bt = *(const float2*)&beta[fp * 2];
  float2 mn = *(const float2*)&mean[fp * 2];
  float2 vr = *(const float2*)&var[fp * 2];
  float gsx = gm.x * rsqrtf(vr.x + BN_EPS);
  float gsy = gm.y * rsqrtf(vr.y + BN_EPS);

  #pragma unroll
  for (int t = 0; t < 8; ++t) {
    int j = hw * 8 + t;
    int node = node0 + j;
    if (node >= N) continue;
    int c0 = lds_cnt[j];
    int c = (c0 < CAP) ? c0 : CAP;
    unsigned us = hb32[(size_t)node * 32 + fp];

    float ax = 0.f, ay = 0.f;
    int q = 0;
    for (; q + 8 <= c; q += 8) {
      int d[8];
      #pragma unroll
      for (int i = 0; i < 8; ++i) {
        int dr = lds_dst[(q + i) * 64 + j];
        d[i] = ((unsigned)dr < (unsigned)N) ? dr : 0;
      }
      unsigned u[8];
      #pragma unroll
      for (int i = 0; i < 8; ++i) u[i] = hbs32[(size_t)d[i] * 32 + fp];
      #pragma unroll
      for (int i = 0; i < 8; ++i) {
        ax += __uint_as_float(u[i] << 16);
        ay += __uint_as_float(u[i] & 0xffff0000u);
      }
    }
    for (; q < c; ++q) {
      int dq = lds_dst[q * 64 + j];
      dq = ((unsigned)dq < (unsigned)N) ? dq : 0;
      unsigned u = hbs32[(size_t)dq * 32 + fp];
      ax += __uint_as_float(u << 16);
      ay += __uint_as_float(u & 0xffff0000u);
    }

    float hx = __uint_as_float(us << 16);
    float hy = __uint_as_float(us & 0xffff0000u);
    float degf = (float)c0;
    float isd_n = rsqrtf((float)((c0 > 0) ? c0 : 1));
    float rx = 0.5f * (isd_n * ax + degf * hx);
    float ry = 0.5f * (isd_n * ay + degf * hy);

    float2 o;
    o.x = (rx - mn.x) * gsx + bt.x;
    o.y = (ry - mn.y) * gsy + bt.y;
    *(float2*)&out[(size_t)node * 64 + fp * 2] = o;
  }
}

__global__ __launch_bounds__(256) void k_agg2_g(const int* __restrict__ cnt,
                                                const int* __restrict__ ell_t,
                                                const unsigned int* __restrict__ hb32,
                                                const float* __restrict__ gamma,
                                                const float* __restrict__ beta,
                                                const float* __restrict__ mean,
                                                const float* __restrict__ var,
                                                float* __restrict__ out, int N) {
  __shared__ int lds_dst[CAP * 64];
  __shared__ int lds_cnt[64];
  int tid = threadIdx.x;
  int node0 = blockIdx.x * 64;

  if (tid < 64) {
    int n = node0 + tid;
    lds_cnt[tid] = (n < N) ? cnt[n] : 0;
  }
  for (int i = tid; i < CAP * 64; i += 256) {
    int j = i & 63;
    int p = i >> 6;
    int n = node0 + j;
    lds_dst[i] = (n < N) ? ell_t[(size_t)p * N + n] : 0;
  }
  __syncthreads();

  int hw = tid >> 5;
  int fp = tid & 31;
  float2 gm = *(const float2*)&gamma[fp * 2];
  float2 bt = *(const float2*)&beta[fp * 2];
  float2 mn = *(const float2*)&mean[fp * 2];
  float2 vr = *(const float2*)&var[fp * 2];
  float gsx = gm.x * rsqrtf(vr.x + BN_EPS);
  float gsy = gm.y * rsqrtf(vr.y + BN_EPS);

  for (int t = 0; t < 8; ++t) {
    int j = hw * 8 + t;
    int node = node0 + j;
    if (node >= N) continue;
    int c0 = lds_cnt[j];
    int c = (c0 < CAP) ? c0 : CAP;
    unsigned us = hb32[(size_t)node * 32 + fp];

    float ax = 0.f, ay = 0.f;
    int q = 0;
    for (; q + 4 <= c; q += 4) {
      int d0 = lds_dst[(q + 0) * 64 + j]; d0 = ((unsigned)d0 < (unsigned)N) ? d0 : 0;
      int d1 = lds_dst[(q + 1) * 64 + j]; d1 = ((unsigned)d1 < (unsigned)N) ? d1 : 0;
      int d2 = lds_dst[(q + 2) * 64 + j]; d2 = ((unsigned)d2 < (unsigned)N) ? d2 : 0;
      int d3 = lds_dst[(q + 3) * 64 + j]; d3 = ((unsigned)d3 < (unsigned)N) ? d3 : 0;
      float s0 = rsqrtf((float)max(cnt[d0], 1));
      float s1 = rsqrtf((float)max(cnt[d1], 1));
      float s2 = rsqrtf((float)max(cnt[d2], 1));
      float s3 = rsqrtf((float)max(cnt[d3], 1));
      unsigned u0 = hb32[(size_t)d0 * 32 + fp];
      unsigned u1 = hb32[(size_t)d1 * 32 + fp];
      unsigned u2 = hb32[(size_t)d2 * 32 + fp];
      unsigned u3 = hb32[(size_t)d3 * 32 + fp];
      ax = fmaf(s0, __uint_as_float(u0 << 16), ax);
      ay = fmaf(s0, __uint_as_float(u0 & 0xffff0000u), ay);
      ax = fmaf(s1, __uint_as_float(u1 << 16), ax);
      ay = fmaf(s1, __uint_as_float(u1 & 0xffff0000u), ay);
      ax = fmaf(s2, __uint_as_float(u2 << 16), ax);
      ay = fmaf(s2, __uint_as_float(u2 & 0xffff0000u), ay);
      ax = fmaf(s3, __uint_as_float(u3 << 16), ax);
      ay = fmaf(s3, __uint_as_float(u3 & 0xffff0000u), ay);
    }
    for (; q < c; ++q) {
      int dq = lds_dst[q * 64 + j];
      dq = ((unsigned)dq < (unsigned)N) ? dq : 0;
      float sq = rsqrtf((float)max(cnt[dq], 1));
      unsigned u = hb32[(size_t)dq * 32 + fp];
      ax = fmaf(sq, __uint_as_float(u << 16), ax);
      ay = fmaf(sq, __uint_as_float(u & 0xffff0000u), ay);
    }

    float hx = __uint_as_float(us << 16);
    float hy = __uint_as_float(us & 0xffff0000u);
    float degf = (float)c0;
    float isd_n = rsqrtf((float)((c0 > 0) ? c0 : 1));
    float rx = 0.5f * (isd_n * ax + degf * hx);
    float ry = 0.5f * (isd_n * ay + degf * hy);

    float2 o;
    o.x = (rx - mn.x) * gsx + bt.x;
    o.y = (ry - mn.y) * gsy + bt.y;
    *(float2*)&out[(size_t)node * 64 + fp * 2] = o;
  }
}

extern "C" void kernel_launch(void* const* d_in, const int* in_sizes, int n_in,
                              void* d_out, int out_size, void* d_ws, size_t ws_size,
                              hipStream_t stream) {
  const float* X     = (const float*)d_in[0];
  const float* W     = (const float*)d_in[1];
  const float* B     = (const float*)d_in[2];
  const float* gamma = (const float*)d_in[3];
  const float* beta  = (const float*)d_in[4];
  const float* mean  = (const float*)d_in[5];
  const float* var   = (const float*)d_in[6];
  const int2*  ei    = (const int2*)d_in[7];

  int N = in_sizes[0] / 128;
  int E = in_sizes[7] / 2;
  float* out = (float*)d_out;

  size_t hb_bytes = (size_t)N * 64 * 2;
  size_t need_hbs = hb_bytes * 2 + (size_t)N * CAP * 4 + (size_t)N * 4;
  int use_hbs = (ws_size >= need_hbs) ? 1 : 0;

  unsigned short* hb;
  unsigned short* hbs;
  int* ell;
  int* cnt;
  if (use_hbs) {
    hb  = (unsigned short*)d_ws;
    hbs = hb + (size_t)N * 64;
    ell = (int*)(hbs + (size_t)N * 64);
    cnt = ell + (size_t)N * CAP;
  } else {
    hb  = (unsigned short*)d_ws;
    hbs = hb;                      // unused
    ell = (int*)(hb + (size_t)N * 64);
    cnt = ell + (size_t)N * CAP;
  }

  // grid size for cooperative launch: all blocks co-resident (cached)
  static int s_grid = 0;
  if (s_grid == 0) {
    int dev = 0;
    hipGetDevice(&dev);
    int cus = 0;
    hipDeviceGetAttribute(&cus, hipDeviceAttributeMultiprocessorCount, dev);
    if (cus <= 0) cus = 256;
    int maxb = 0;
    hipOccupancyMaxActiveBlocksPerMultiprocessor(&maxb, k_all, 256, 0);
    if (maxb <= 0) maxb = 1;
    s_grid = cus * maxb;
    if (s_grid > 4096) s_grid = 4096;
  }

  void* args[] = {(void*)&X, (void*)&W, (void*)&B, (void*)&gamma, (void*)&beta,
                  (void*)&mean, (void*)&var, (void*)&ei, (void*)&hb, (void*)&hbs,
                  (void*)&ell, (void*)&cnt, (void*)&out, (void*)&N, (void*)&E,
                  (void*)&use_hbs};
  hipError_t err = hipLaunchCooperativeKernel((const void*)k_all, dim3(s_grid),
                                              dim3(256), args, 0, stream);
  if (err == hipSuccess) return;

  // ---------- fallback: round-5 multi-dispatch path ----------
  hipMemsetAsync(cnt, 0, (size_t)N * sizeof(int), stream);
  int Gs = (E + 255) / 256;
  int Gg = (N + 63) / 64;
  int g7 = (Gg + 1) / 2;
  int g5 = (Gs + 4) / 5;
  int groups = (g7 > g5) ? g7 : g5;
  int Ga = (N + 63) / 64;

  k_fused<<<groups * 7, 256, 0, stream>>>(X, W, B, hb, N, Gg, ei, cnt, ell, E, Gs);
  if (use_hbs) {
    k_scale<<<(N * 8 + 255) / 256, 256, 0, stream>>>((const unsigned int*)hb, cnt,
                                                     (unsigned int*)hbs, N);
    k_agg2<<<Ga, 256, 0, stream>>>(cnt, ell, (const unsigned int*)hb,
                                   (const unsigned int*)hbs,
                                   gamma, beta, mean, var, out, N);
  } else {
    k_agg2_g<<<Ga, 256, 0, stream>>>(cnt, ell, (const unsigned int*)hb,
                                     gamma, beta, mean, var, out, N);
  }
}

// Round 7
// 179.254 us; speedup vs baseline: 3.8705x; 3.8705x over previous
//
#include <hip/hip_runtime.h>

#define BN_EPS 0.001f
#define CAP 32   // deg = 1 + Poisson(~9); P(deg >= 32) ~ 1e-22 -> safe
#define NPART 8  // node partitions (match 8 XCDs; bid%8 ~ XCD round-robin heuristic)
#define SEGE 2048  // edges per scatter segment (256 threads x 8)

typedef __attribute__((ext_vector_type(8))) short bf16x8;
typedef __attribute__((ext_vector_type(4))) float f32x4;

__device__ __forceinline__ unsigned short f2bf(float f) {
  unsigned u = __float_as_uint(f);
  u += 0x7fffu + ((u >> 16) & 1u);
  return (unsigned short)(u >> 16);
}
__device__ __forceinline__ unsigned scale2(unsigned u, float s) {
  float lo = __uint_as_float(u << 16) * s;
  float hi = __uint_as_float(u & 0xffff0000u) * s;
  return (((unsigned)f2bf(hi)) << 16) | (unsigned)f2bf(lo);
}

// ---------- FUSED: interleaved 5:2 partitioned-scatter / MFMA-gemm ----------
// Scatter unit u: partition p = u&7, segment s = u>>3. Block scans 2048 edges
// (coalesced, L3-resident re-reads) and places only src in [p*N/8,(p+1)*N/8):
// dirty footprint/partition = 1.6MB ell + 0.4MB cnt -> L2-resident -> dense
// writeback instead of ~1M random 64B lines (the 0.95 TB/s wall).
__global__ __launch_bounds__(256) void k_fused(
    const float* __restrict__ X, const float* __restrict__ W,
    const float* __restrict__ B, unsigned short* __restrict__ hb, int N, int Gg,
    const int2* __restrict__ ei, int* __restrict__ cnt,
    int* __restrict__ ell_t, int E, int Gs) {
  __shared__ float WtF[4096];  // 16 KB: Wt[col][k] bf16, XOR-swizzled

  int g = blockIdx.x / 7;
  int r = blockIdx.x % 7;
  int tid = threadIdx.x;

  if (r >= 2) {
    // ----- scatter role -----
    int u = g * 5 + (r - 2);
    if (u >= Gs) return;
    int p   = u & (NPART - 1);
    int seg = u >> 3;
    int lo = (int)((size_t)p * N / NPART);
    int hi = (int)((size_t)(p + 1) * N / NPART);
    int base = seg * SEGE;
    #pragma unroll
    for (int i = 0; i < 8; ++i) {
      int e = base + i * 256 + tid;
      if (e < E) {
        int2 sd = ei[e];
        if (sd.x >= lo && sd.x < hi) {
          int pos = atomicAdd(&cnt[sd.x], 1);
          if (pos < CAP) ell_t[(size_t)pos * N + sd.x] = sd.y;
        }
      }
    }
    return;
  }

  // ----- gemm role: hb = bf16(X@W + b) via MFMA, 64 rows x 64 cols per block -----
  int tile = g * 2 + r;
  if (tile >= Gg) return;

  char* Wt = (char*)WtF;
  const float4* W4 = (const float4*)W;
  for (int i = tid; i < 2048; i += 256) {
    float4 v = W4[i];
    int k = i >> 4;
    int col0 = (i & 15) << 2;
    int kb2 = k << 1;
    *(unsigned short*)(Wt + (((col0 + 0) << 8) | (kb2 ^ (((col0 + 0) & 7) << 4)))) = f2bf(v.x);
    *(unsigned short*)(Wt + (((col0 + 1) << 8) | (kb2 ^ (((col0 + 1) & 7) << 4)))) = f2bf(v.y);
    *(unsigned short*)(Wt + (((col0 + 2) << 8) | (kb2 ^ (((col0 + 2) & 7) << 4)))) = f2bf(v.z);
    *(unsigned short*)(Wt + (((col0 + 3) << 8) | (kb2 ^ (((col0 + 3) & 7) << 4)))) = f2bf(v.w);
  }
  __syncthreads();

  int lane = tid & 63;
  int w = tid >> 6;
  int l15 = lane & 15;
  int lk = lane >> 4;

  int row0 = tile * 64;
  int rA = row0 + w * 16 + l15;
  bool rowok = rA < N;
  const float* xp = X + (size_t)rA * 128 + (lk << 3);

  f32x4 acc[4];
  #pragma unroll
  for (int n = 0; n < 4; ++n) {
    float bv = B[(n << 4) + l15];
    acc[n] = (f32x4){bv, bv, bv, bv};
  }

  #pragma unroll
  for (int kb = 0; kb < 4; ++kb) {
    bf16x8 af = {0, 0, 0, 0, 0, 0, 0, 0};
    if (rowok) {
      float4 x0 = *(const float4*)(xp + kb * 32);
      float4 x1 = *(const float4*)(xp + kb * 32 + 4);
      af[0] = (short)f2bf(x0.x); af[1] = (short)f2bf(x0.y);
      af[2] = (short)f2bf(x0.z); af[3] = (short)f2bf(x0.w);
      af[4] = (short)f2bf(x1.x); af[5] = (short)f2bf(x1.y);
      af[6] = (short)f2bf(x1.z); af[7] = (short)f2bf(x1.w);
    }
    int kbyte = (kb << 6) | (lk << 4);
    #pragma unroll
    for (int n = 0; n < 4; ++n) {
      int col = (n << 4) + l15;
      bf16x8 bfr = *(const bf16x8*)(Wt + ((col << 8) | (kbyte ^ ((col & 7) << 4))));
      acc[n] = __builtin_amdgcn_mfma_f32_16x16x32_bf16(af, bfr, acc[n], 0, 0, 0);
    }
  }

  // C/D layout (verified m89/m91): col = lane&15, row = (lane>>4)*4 + reg
  int rbase = row0 + w * 16 + (lk << 2);
  #pragma unroll
  for (int n = 0; n < 4; ++n) {
    #pragma unroll
    for (int q = 0; q < 4; ++q) {
      int row = rbase + q;
      if (row < N) hb[(size_t)row * 64 + (n << 4) + l15] = f2bf(acc[n][q]);
    }
  }
}

// ---------- scale pass: hbs = bf16(rsqrt(deg) * hb), dense, ~26MB traffic ----------
__global__ __launch_bounds__(256) void k_scale(const unsigned int* __restrict__ hb32,
                                               const int* __restrict__ cnt,
                                               unsigned int* __restrict__ hbs32, int N) {
  int t = blockIdx.x * 256 + threadIdx.x;
  int node = t >> 3;           // 8 threads per node (8 x uint4 = 128B row)
  int q = t & 7;
  if (node >= N) return;
  int c = cnt[node];
  float s = rsqrtf((float)((c > 0) ? c : 1));
  uint4 v = ((const uint4*)(hb32 + (size_t)node * 32))[q];
  v.x = scale2(v.x, s); v.y = scale2(v.y, s);
  v.z = scale2(v.z, s); v.w = scale2(v.w, s);
  ((uint4*)(hbs32 + (size_t)node * 32))[q] = v;
}

// ---------- aggregate + self + BN from TRANSPOSED ELL ----------
__global__ __launch_bounds__(256) void k_agg2(const int* __restrict__ cnt,
                                              const int* __restrict__ ell_t,
                                              const unsigned int* __restrict__ hb32,
                                              const unsigned int* __restrict__ hbs32,
                                              const float* __restrict__ gamma,
                                              const float* __restrict__ beta,
                                              const float* __restrict__ mean,
                                              const float* __restrict__ var,
                                              float* __restrict__ out, int N) {
  __shared__ int lds_dst[CAP * 64];   // [p][j] 8 KB
  __shared__ int lds_cnt[64];

  int tid = threadIdx.x;
  int node0 = blockIdx.x * 64;

  if (tid < 64) {
    int n = node0 + tid;
    lds_cnt[tid] = (n < N) ? cnt[n] : 0;
  }
  for (int i = tid; i < CAP * 64; i += 256) {
    int j = i & 63;
    int p = i >> 6;
    int n = node0 + j;
    lds_dst[i] = (n < N) ? ell_t[(size_t)p * N + n] : 0;
  }
  __syncthreads();

  int hw = tid >> 5;
  int fp = tid & 31;

  float2 gm = *(const float2*)&gamma[fp * 2];
  float2 bt = *(const float2*)&beta[fp * 2];
  float2 mn = *(const float2*)&mean[fp * 2];
  float2 vr = *(const float2*)&var[fp * 2];
  float gsx = gm.x * rsqrtf(vr.x + BN_EPS);
  float gsy = gm.y * rsqrtf(vr.y + BN_EPS);

  #pragma unroll
  for (int t = 0; t < 8; ++t) {
    int j = hw * 8 + t;
    int node = node0 + j;
    if (node >= N) continue;
    int c0 = lds_cnt[j];
    int c = (c0 < CAP) ? c0 : CAP;
    unsigned us = hb32[(size_t)node * 32 + fp];   // self row (raw h), issue early

    float ax = 0.f, ay = 0.f;
    int q = 0;
    for (; q + 8 <= c; q += 8) {
      int d[8];
      #pragma unroll
      for (int i = 0; i < 8; ++i) {
        int dr = lds_dst[(q + i) * 64 + j];
        d[i] = ((unsigned)dr < (unsigned)N) ? dr : 0;
      }
      unsigned u[8];
      #pragma unroll
      for (int i = 0; i < 8; ++i) u[i] = hbs32[(size_t)d[i] * 32 + fp];
      #pragma unroll
      for (int i = 0; i < 8; ++i) {
        ax += __uint_as_float(u[i] << 16);
        ay += __uint_as_float(u[i] & 0xffff0000u);
      }
    }
    if (q + 4 <= c) {
      int d0 = lds_dst[(q + 0) * 64 + j]; d0 = ((unsigned)d0 < (unsigned)N) ? d0 : 0;
      int d1 = lds_dst[(q + 1) * 64 + j]; d1 = ((unsigned)d1 < (unsigned)N) ? d1 : 0;
      int d2 = lds_dst[(q + 2) * 64 + j]; d2 = ((unsigned)d2 < (unsigned)N) ? d2 : 0;
      int d3 = lds_dst[(q + 3) * 64 + j]; d3 = ((unsigned)d3 < (unsigned)N) ? d3 : 0;
      unsigned u0 = hbs32[(size_t)d0 * 32 + fp];
      unsigned u1 = hbs32[(size_t)d1 * 32 + fp];
      unsigned u2 = hbs32[(size_t)d2 * 32 + fp];
      unsigned u3 = hbs32[(size_t)d3 * 32 + fp];
      ax += __uint_as_float(u0 << 16); ay += __uint_as_float(u0 & 0xffff0000u);
      ax += __uint_as_float(u1 << 16); ay += __uint_as_float(u1 & 0xffff0000u);
      ax += __uint_as_float(u2 << 16); ay += __uint_as_float(u2 & 0xffff0000u);
      ax += __uint_as_float(u3 << 16); ay += __uint_as_float(u3 & 0xffff0000u);
      q += 4;
    }
    for (; q < c; ++q) {
      int dq = lds_dst[q * 64 + j];
      dq = ((unsigned)dq < (unsigned)N) ? dq : 0;
      unsigned u = hbs32[(size_t)dq * 32 + fp];
      ax += __uint_as_float(u << 16);
      ay += __uint_as_float(u & 0xffff0000u);
    }

    float hx = __uint_as_float(us << 16);
    float hy = __uint_as_float(us & 0xffff0000u);
    float degf = (float)c0;
    float isd_n = rsqrtf((float)((c0 > 0) ? c0 : 1));
    float rx = 0.5f * (isd_n * ax + degf * hx);
    float ry = 0.5f * (isd_n * ay + degf * hy);

    float2 o;
    o.x = (rx - mn.x) * gsx + bt.x;
    o.y = (ry - mn.y) * gsy + bt.y;
    *(float2*)&out[(size_t)node * 64 + fp * 2] = o;
  }
}

// ---------- fallback (ws too small for hbs): gather raw hb + per-dst scale ----------
__global__ __launch_bounds__(256) void k_agg2_g(const int* __restrict__ cnt,
                                                const int* __restrict__ ell_t,
                                                const unsigned int* __restrict__ hb32,
                                                const float* __restrict__ gamma,
                                                const float* __restrict__ beta,
                                                const float* __restrict__ mean,
                                                const float* __restrict__ var,
                                                float* __restrict__ out, int N) {
  __shared__ int lds_dst[CAP * 64];
  __shared__ int lds_cnt[64];

  int tid = threadIdx.x;
  int node0 = blockIdx.x * 64;

  if (tid < 64) {
    int n = node0 + tid;
    lds_cnt[tid] = (n < N) ? cnt[n] : 0;
  }
  for (int i = tid; i < CAP * 64; i += 256) {
    int j = i & 63;
    int p = i >> 6;
    int n = node0 + j;
    lds_dst[i] = (n < N) ? ell_t[(size_t)p * N + n] : 0;
  }
  __syncthreads();

  int hw = tid >> 5;
  int fp = tid & 31;

  float2 gm = *(const float2*)&gamma[fp * 2];
  float2 bt = *(const float2*)&beta[fp * 2];
  float2 mn = *(const float2*)&mean[fp * 2];
  float2 vr = *(const float2*)&var[fp * 2];
  float gsx = gm.x * rsqrtf(vr.x + BN_EPS);
  float gsy = gm.y * rsqrtf(vr.y + BN_EPS);

  for (int t = 0; t < 8; ++t) {
    int j = hw * 8 + t;
    int node = node0 + j;
    if (node >= N) continue;
    int c0 = lds_cnt[j];
    int c = (c0 < CAP) ? c0 : CAP;
    unsigned us = hb32[(size_t)node * 32 + fp];

    float ax = 0.f, ay = 0.f;
    int q = 0;
    for (; q + 4 <= c; q += 4) {
      int d0 = lds_dst[(q + 0) * 64 + j]; d0 = ((unsigned)d0 < (unsigned)N) ? d0 : 0;
      int d1 = lds_dst[(q + 1) * 64 + j]; d1 = ((unsigned)d1 < (unsigned)N) ? d1 : 0;
      int d2 = lds_dst[(q + 2) * 64 + j]; d2 = ((unsigned)d2 < (unsigned)N) ? d2 : 0;
      int d3 = lds_dst[(q + 3) * 64 + j]; d3 = ((unsigned)d3 < (unsigned)N) ? d3 : 0;
      float s0 = rsqrtf((float)max(cnt[d0], 1));
      float s1 = rsqrtf((float)max(cnt[d1], 1));
      float s2 = rsqrtf((float)max(cnt[d2], 1));
      float s3 = rsqrtf((float)max(cnt[d3], 1));
      unsigned u0 = hb32[(size_t)d0 * 32 + fp];
      unsigned u1 = hb32[(size_t)d1 * 32 + fp];
      unsigned u2 = hb32[(size_t)d2 * 32 + fp];
      unsigned u3 = hb32[(size_t)d3 * 32 + fp];
      ax = fmaf(s0, __uint_as_float(u0 << 16), ax);
      ay = fmaf(s0, __uint_as_float(u0 & 0xffff0000u), ay);
      ax = fmaf(s1, __uint_as_float(u1 << 16), ax);
      ay = fmaf(s1, __uint_as_float(u1 & 0xffff0000u), ay);
      ax = fmaf(s2, __uint_as_float(u2 << 16), ax);
      ay = fmaf(s2, __uint_as_float(u2 & 0xffff0000u), ay);
      ax = fmaf(s3, __uint_as_float(u3 << 16), ax);
      ay = fmaf(s3, __uint_as_float(u3 & 0xffff0000u), ay);
    }
    for (; q < c; ++q) {
      int dq = lds_dst[q * 64 + j];
      dq = ((unsigned)dq < (unsigned)N) ? dq : 0;
      float sq = rsqrtf((float)max(cnt[dq], 1));
      unsigned u = hb32[(size_t)dq * 32 + fp];
      ax = fmaf(sq, __uint_as_float(u << 16), ax);
      ay = fmaf(sq, __uint_as_float(u & 0xffff0000u), ay);
    }

    float hx = __uint_as_float(us << 16);
    float hy = __uint_as_float(us & 0xffff0000u);
    float degf = (float)c0;
    float isd_n = rsqrtf((float)((c0 > 0) ? c0 : 1));
    float rx = 0.5f * (isd_n * ax + degf * hx);
    float ry = 0.5f * (isd_n * ay + degf * hy);

    float2 o;
    o.x = (rx - mn.x) * gsx + bt.x;
    o.y = (ry - mn.y) * gsy + bt.y;
    *(float2*)&out[(size_t)node * 64 + fp * 2] = o;
  }
}

extern "C" void kernel_launch(void* const* d_in, const int* in_sizes, int n_in,
                              void* d_out, int out_size, void* d_ws, size_t ws_size,
                              hipStream_t stream) {
  const float* X     = (const float*)d_in[0];
  const float* W     = (const float*)d_in[1];
  const float* B     = (const float*)d_in[2];
  const float* gamma = (const float*)d_in[3];
  const float* beta  = (const float*)d_in[4];
  const float* mean  = (const float*)d_in[5];
  const float* var   = (const float*)d_in[6];
  const int2*  ei    = (const int2*)d_in[7];

  int N = in_sizes[0] / 128;
  int E = in_sizes[7] / 2;
  float* out = (float*)d_out;

  size_t hb_elems = (size_t)N * 64;
  size_t need_hbs = hb_elems * 2 * 2 + (size_t)N * CAP * 4 + (size_t)N * 4;

  int Gs = NPART * ((E + SEGE - 1) / SEGE);   // partitioned scatter units
  int Gg = (N + 63) / 64;                     // gemm tiles
  int g7 = (Gg + 1) / 2;
  int g5 = (Gs + 4) / 5;
  int groups = (g7 > g5) ? g7 : g5;
  int Ga = (N + 63) / 64;                     // agg blocks (64 nodes each)

  if (ws_size >= need_hbs) {
    // layout: hb | hbs | ell_t | cnt
    unsigned short* hb  = (unsigned short*)d_ws;
    unsigned short* hbs = hb + hb_elems;
    int*            ell = (int*)(hbs + hb_elems);
    int*            cnt = ell + (size_t)N * CAP;

    hipMemsetAsync(cnt, 0, (size_t)N * sizeof(int), stream);
    k_fused<<<groups * 7, 256, 0, stream>>>(X, W, B, hb, N, Gg, ei, cnt, ell, E, Gs);
    k_scale<<<(N * 8 + 255) / 256, 256, 0, stream>>>((const unsigned int*)hb, cnt,
                                                     (unsigned int*)hbs, N);
    k_agg2<<<Ga, 256, 0, stream>>>(cnt, ell, (const unsigned int*)hb,
                                   (const unsigned int*)hbs,
                                   gamma, beta, mean, var, out, N);
  } else {
    // layout: hb | ell_t | cnt
    unsigned short* hb  = (unsigned short*)d_ws;
    int*            ell = (int*)(hb + hb_elems);
    int*            cnt = ell + (size_t)N * CAP;

    hipMemsetAsync(cnt, 0, (size_t)N * sizeof(int), stream);
    k_fused<<<groups * 7, 256, 0, stream>>>(X, W, B, hb, N, Gg, ei, cnt, ell, E, Gs);
    k_agg2_g<<<Ga, 256, 0, stream>>>(cnt, ell, (const unsigned int*)hb,
                                     gamma, beta, mean, var, out, N);
  }
}